// Round 9
// baseline (133.271 us; speedup 1.0000x reference)
//
#include <hip/hip_runtime.h>
#include <stdint.h>

typedef int   i32x8  __attribute__((ext_vector_type(8)));
typedef float f32x16 __attribute__((ext_vector_type(16)));

#define B_ROWS 8192
#define D_DIM  512

// monotone float<->uint encoding: enc order == float order (uint atomicMin
// == float min). f>=0: set sign bit; f<0: bitwise NOT.
__device__ __forceinline__ uint32_t enc_f32(float f) {
  uint32_t s = __float_as_uint(f);
  return (s & 0x80000000u) ? ~s : (s | 0x80000000u);
}
__device__ __forceinline__ float dec_f32(uint32_t e) {
  uint32_t s = (e & 0x80000000u) ? (e ^ 0x80000000u) : ~e;
  return __uint_as_float(s);
}

// ---------------------------------------------------------------------------
// Transposed fp8 layout ("frag-ready"): tile(rowBlk, kBlk) = 32 rows x 64 K
// = 2048 B at offset (rowBlk*8 + kBlk)*2048. Byte for (row = rowBlk*32 + r31,
// k = kBlk*64 + h*32 + j*16 + b) is at j*1024 + (h*32 + r31)*16 + b.
// A wave's 32x32x64 operand frag load = two coalesced 1 KB reads at
// {base + lane*16, +1024} (lane = h*32 + r31) — matches the HW-validated
// 32x32x64 A/B mapping: row = lane&31, k = (lane>>5)*32 + byte.
// ---------------------------------------------------------------------------

// ---------------------------------------------------------------------------
// Kernel 1: per-row normalize (fp32 -> fp8 e4m3) + cos(anchor, positive),
// storing a8t/p8t in the transposed frag-ready layout (R8-proven).
// ---------------------------------------------------------------------------
__global__ __launch_bounds__(256) void norm_kernel(
    const float* __restrict__ anchor, const float* __restrict__ positive,
    uint8_t* __restrict__ a8t, uint8_t* __restrict__ p8t,
    float* __restrict__ cos_ap, uint32_t* __restrict__ minenc)
{
  const int wave = threadIdx.x >> 6, lane = threadIdx.x & 63;
  const int r = blockIdx.x * 4 + wave;

  const float4* av = (const float4*)(anchor   + (size_t)r * D_DIM) + lane * 2;
  const float4* pv = (const float4*)(positive + (size_t)r * D_DIM) + lane * 2;
  float4 a0 = av[0], a1 = av[1];
  float4 p0 = pv[0], p1 = pv[1];

  float sa = a0.x*a0.x + a0.y*a0.y + a0.z*a0.z + a0.w*a0.w
           + a1.x*a1.x + a1.y*a1.y + a1.z*a1.z + a1.w*a1.w;
  float sp = p0.x*p0.x + p0.y*p0.y + p0.z*p0.z + p0.w*p0.w
           + p1.x*p1.x + p1.y*p1.y + p1.z*p1.z + p1.w*p1.w;
  float dp = a0.x*p0.x + a0.y*p0.y + a0.z*p0.z + a0.w*p0.w
           + a1.x*p1.x + a1.y*p1.y + a1.z*p1.z + a1.w*p1.w;

#pragma unroll
  for (int d = 1; d < 64; d <<= 1) {
    sa += __shfl_xor(sa, d);
    sp += __shfl_xor(sp, d);
    dp += __shfl_xor(dp, d);
  }

  const float na = sqrtf(sa), np = sqrtf(sp);
  const float ia = 1.0f / na, ip = 1.0f / np;

  float na0 = a0.x*ia, na1 = a0.y*ia, na2 = a0.z*ia, na3 = a0.w*ia;
  float na4 = a1.x*ia, na5 = a1.y*ia, na6 = a1.z*ia, na7 = a1.w*ia;
  float np0 = p0.x*ip, np1 = p0.y*ip, np2 = p0.z*ip, np3 = p0.w*ip;
  float np4 = p1.x*ip, np5 = p1.y*ip, np6 = p1.z*ip, np7 = p1.w*ip;

  uint32_t aw0 = __builtin_amdgcn_cvt_pk_fp8_f32(na0, na1, 0,  false);
  aw0          = __builtin_amdgcn_cvt_pk_fp8_f32(na2, na3, aw0, true);
  uint32_t aw1 = __builtin_amdgcn_cvt_pk_fp8_f32(na4, na5, 0,  false);
  aw1          = __builtin_amdgcn_cvt_pk_fp8_f32(na6, na7, aw1, true);
  uint32_t pw0 = __builtin_amdgcn_cvt_pk_fp8_f32(np0, np1, 0,  false);
  pw0          = __builtin_amdgcn_cvt_pk_fp8_f32(np2, np3, pw0, true);
  uint32_t pw1 = __builtin_amdgcn_cvt_pk_fp8_f32(np4, np5, 0,  false);
  pw1          = __builtin_amdgcn_cvt_pk_fp8_f32(np6, np7, pw1, true);

  // gather chunk c = lane&31: bytes [c*16, c*16+16) from lanes 2c, 2c+1
  const int c = lane & 31;
  const uint32_t A0 = __shfl(aw0, c*2),   A1 = __shfl(aw1, c*2);
  const uint32_t A2 = __shfl(aw0, c*2+1), A3 = __shfl(aw1, c*2+1);
  const uint32_t P0 = __shfl(pw0, c*2),   P1 = __shfl(pw1, c*2);
  const uint32_t P2 = __shfl(pw0, c*2+1), P3 = __shfl(pw1, c*2+1);

  const int kBlk = c >> 2, h = (c >> 1) & 1, j = c & 1;
  const size_t off = ((size_t)((r >> 5) * 8 + kBlk)) * 2048 + j * 1024
                   + ((h * 32 + (r & 31)) * 16);
  if (lane < 32) *(uint4*)(a8t + off) = make_uint4(A0, A1, A2, A3);
  else           *(uint4*)(p8t + off) = make_uint4(P0, P1, P2, P3);

  if (lane == 0) {
    cos_ap[r] = dp / fmaxf(na * np, 1e-8f);
    minenc[r] = 0xFFFFFFFFu;   // +inf in monotone encoding
  }
}

// ---------------------------------------------------------------------------
// global -> LDS direct load, 16B per lane (dest = wave-uniform base + lane*16).
// ---------------------------------------------------------------------------
__device__ __forceinline__ void load16_to_lds(const void* g, void* l) {
  __builtin_amdgcn_global_load_lds(
      (__attribute__((address_space(1))) uint32_t*)(uintptr_t)(g),
      (__attribute__((address_space(3))) uint32_t*)(uintptr_t)(l),
      16, 0, 0);
}

// ---------------------------------------------------------------------------
// Kernel 2: sim = A_n * P_n^T via 32x32x64 MX-fp8 MFMA (scale=1.0), fused
// diag-masked row-min -> device atomicMin.
//
// R8 post-mortem: every structure saturates ~9-13 TB/s of L2-delivered
// operand traffic (per-XCD L2 return BW is the wall); R8 carried 2x
// redundancy (4 waves load identical A). R9: A staged ONCE per block into
// LDS via global_load_lds (frag-ready 2 KB tiles -> two full-line 1 KB
// chunks; conflict-free b128 frag reads), B register-direct from global
// (R8-proven). Traffic 786 -> 384 MB. One barrier per kb; its vmcnt drain
// lands an mfma-block after issue. NO __threadfence (R5/R6 lesson).
// Block 128m x 256n, 4 waves x (128m x 64n), 8 kBlks. XCD swizzle.
// ---------------------------------------------------------------------------
__global__ __launch_bounds__(256, 2) void simmin_kernel(
    const uint8_t* __restrict__ a8t, const uint8_t* __restrict__ p8t,
    uint32_t* __restrict__ minenc)
{
  __shared__ __attribute__((aligned(16))) uint8_t Albuf[2][4 * 2048];
  __shared__ float redmin[4][128];

  const int tid  = threadIdx.x;
  const int lane = tid & 63;
  const int wave = tid >> 6;        // wave owns cols [wave*64, wave*64+64)
  const int half = lane >> 5;
  const int r31  = lane & 31;

  const int bid = blockIdx.x;
  const int blockRow = (bid & 7) * 8 + ((bid >> 3) & 7);  // 0..63
  const int blockCol = bid >> 6;                          // 0..31

  f32x16 acc[4][2];
#pragma unroll
  for (int i = 0; i < 4; i++)
#pragma unroll
    for (int j = 0; j < 2; j++)
#pragma unroll
      for (int e = 0; e < 16; e++) acc[i][j][e] = 0.f;

  // ---- A staging: wave w copies frag-tile (blockRow*4 + w, kb) = 2 KB
  // (two 1 KB full-line glds chunks) into Albuf[buf][w*2048 .. +2048).
  const uint8_t* aStage = a8t + ((size_t)(blockRow * 4 + wave)) * (8 * 2048)
                        + lane * 16;
  auto stageA = [&](int kb, int buf) {
    const uint8_t* src = aStage + (size_t)kb * 2048;
    load16_to_lds(src,        &Albuf[buf][wave * 2048]);
    load16_to_lds(src + 1024, &Albuf[buf][wave * 2048 + 1024]);
  };

  // ---- B direct from global (register double-buffer)
  const uint8_t* pT[2];
#pragma unroll
  for (int nf = 0; nf < 2; nf++)
    pT[nf] = p8t + ((size_t)(blockCol * 8 + wave * 2 + nf)) * (8 * 2048)
           + lane * 16;

  i32x8 bf[2][2];
  auto loadB = [&](int kb, int buf) {
#pragma unroll
    for (int nf = 0; nf < 2; nf++) {
      const uint8_t* t = pT[nf] + (size_t)kb * 2048;
      const int4 lo = *(const int4*)t;
      const int4 hi = *(const int4*)(t + 1024);
      bf[buf][nf] = (i32x8){lo.x, lo.y, lo.z, lo.w, hi.x, hi.y, hi.z, hi.w};
    }
  };

  stageA(0, 0);
  loadB(0, 0);

#pragma unroll
  for (int kb = 0; kb < 8; kb++) {
    const int cur = kb & 1, nxt = cur ^ 1;
    __syncthreads();   // Albuf[cur] staged (vmcnt drain covers prior-iter glds)

    // A frags from LDS (conflict-free b128: lane*16 over 1 KB contiguous)
    i32x8 af[4];
#pragma unroll
    for (int mf = 0; mf < 4; mf++) {
      const int4 lo = *(const int4*)&Albuf[cur][mf * 2048 + lane * 16];
      const int4 hi = *(const int4*)&Albuf[cur][mf * 2048 + 1024 + lane * 16];
      af[mf] = (i32x8){lo.x, lo.y, lo.z, lo.w, hi.x, hi.y, hi.z, hi.w};
    }

    if (kb < 7) { stageA(kb + 1, nxt); loadB(kb + 1, nxt); }  // prefetch

#pragma unroll
    for (int mf = 0; mf < 4; mf++)
#pragma unroll
      for (int nf = 0; nf < 2; nf++)
        acc[mf][nf] = __builtin_amdgcn_mfma_scale_f32_32x32x64_f8f6f4(
            af[mf], bf[cur][nf], acc[mf][nf],
            0, 0,                 // cbsz=fp8(e4m3) A, blgp=fp8(e4m3) B
            0, 0x7F7F7F7F,        // scale A (2^0)
            0, 0x7F7F7F7F);       // scale B (2^0)
  }

  // ---- epilogue (HW-validated 32x32 C/D layout): diag-masked row-min
  // row = (g&3) + 8*(g>>2) + 4*half, col = lane&31
  float rm[4][16];
#pragma unroll
  for (int mf = 0; mf < 4; mf++)
#pragma unroll
    for (int g = 0; g < 16; g++) rm[mf][g] = 3.0e38f;

#pragma unroll
  for (int mf = 0; mf < 4; mf++) {
#pragma unroll
    for (int nf = 0; nf < 2; nf++) {
      const int col = blockCol * 256 + wave * 64 + nf * 32 + r31;
#pragma unroll
      for (int g = 0; g < 16; g++) {
        const int row = blockRow * 128 + mf * 32 + (g & 3) + 8 * (g >> 2) + 4 * half;
        const float v = acc[mf][nf][g];
        rm[mf][g] = (row == col) ? rm[mf][g] : fminf(rm[mf][g], v);
      }
    }
  }
#pragma unroll
  for (int d = 1; d < 32; d <<= 1)
#pragma unroll
    for (int mf = 0; mf < 4; mf++)
#pragma unroll
      for (int g = 0; g < 16; g++)
        rm[mf][g] = fminf(rm[mf][g], __shfl_xor(rm[mf][g], d));

  if (r31 == 0) {
#pragma unroll
    for (int mf = 0; mf < 4; mf++)
#pragma unroll
      for (int g = 0; g < 16; g++)
        redmin[wave][mf * 32 + (g & 3) + 8 * (g >> 2) + 4 * half] = rm[mf][g];
  }
  __syncthreads();

  if (tid < 128) {
    const float m = fminf(fminf(redmin[0][tid], redmin[1][tid]),
                          fminf(redmin[2][tid], redmin[3][tid]));
    atomicMin(&minenc[blockRow * 128 + tid], enc_f32(m));  // device-scope
  }
}

// ---------------------------------------------------------------------------
// Kernel 3: single block (1024 thr) — decode row-mins, loss, mean, store.
// ---------------------------------------------------------------------------
__global__ __launch_bounds__(1024) void finalize_kernel(
    const uint32_t* __restrict__ minenc, const float* __restrict__ cos_ap,
    float* __restrict__ out)
{
  float sum = 0.0f;
#pragma unroll
  for (int r = threadIdx.x; r < B_ROWS; r += 1024)
    sum += fmaxf(0.0f, 1.0f + cos_ap[r] - dec_f32(minenc[r]));

#pragma unroll
  for (int d = 1; d < 64; d <<= 1) sum += __shfl_xor(sum, d);
  __shared__ float s[16];
  if ((threadIdx.x & 63) == 0) s[threadIdx.x >> 6] = sum;
  __syncthreads();
  if (threadIdx.x < 64) {
    float t = (threadIdx.x < 16) ? s[threadIdx.x] : 0.0f;
#pragma unroll
    for (int d = 1; d < 16; d <<= 1) t += __shfl_xor(t, d);
    if (threadIdx.x == 0) out[0] = t * (1.0f / (float)B_ROWS);
  }
}

// ---------------------------------------------------------------------------
extern "C" void kernel_launch(void* const* d_in, const int* in_sizes, int n_in,
                              void* d_out, int out_size, void* d_ws, size_t ws_size,
                              hipStream_t stream) {
  const float* anchor   = (const float*)d_in[0];
  const float* positive = (const float*)d_in[1];

  char* ws = (char*)d_ws;
  uint8_t*  a8t    = (uint8_t*)(ws);                                // 4 MB
  uint8_t*  p8t    = (uint8_t*)(ws + (4ull << 20));                 // 4 MB
  float*    cos_ap = (float*)(ws + (8ull << 20));                   // 32 KB
  uint32_t* minenc = (uint32_t*)(ws + (8ull << 20) + (32ull << 10));// 32 KB
  float*    out = (float*)d_out;

  norm_kernel<<<B_ROWS / 4, 256, 0, stream>>>(anchor, positive, a8t, p8t,
                                              cos_ap, minenc);
  simmin_kernel<<<2048, 256, 0, stream>>>(a8t, p8t, minenc);
  finalize_kernel<<<1, 1024, 0, stream>>>(minenc, cos_ap, out);
}